// Round 1
// baseline (367.280 us; speedup 1.0000x reference)
//
#include <hip/hip_runtime.h>

// Problem constants
#define B_    32
#define T_    12
#define TM1   11
#define K_    16
#define DIM_  512
#define H0_   512
#define H1_   256
#define NROWS (B_*TM1*K_)          // 5632 rows of O_t (and of U, V)
#define NBT   (B_*TM1)             // 352 (b,t) cells
#define E_ELEMS (NBT*256*H1_)      // 23,068,672 floats of e
// ws layout: U [NROWS][512] floats, then V [NROWS][512] floats -> 23,068,672 bytes

__device__ __forceinline__ float relu_f(float x) { return x > 0.f ? x : 0.f; }

// ---------------------------------------------------------------------------
// Kernel 1: U = O_t @ W0[0:512,:], V = O_t @ W0[512:1024,:]
// Treated as one GEMM, M=5632, N=1024 (8 U-tiles + 8 V-tiles of 64), K=512.
// Block tile 64x64, 256 threads, 4x4 micro-tile, KC=16.
// ---------------------------------------------------------------------------
__global__ __launch_bounds__(256) void k_uv(const float* __restrict__ O,
                                            const float* __restrict__ W0,
                                            float* __restrict__ ws)
{
    __shared__ alignas(16) float As[16][68];   // [k][m], pad to 68 (16B-aligned rows)
    __shared__ alignas(16) float Bs[16][68];   // [k][n]

    const int bx = blockIdx.x;        // 0..87  M tiles
    const int by = blockIdx.y;        // 0..15  N tiles (0..7 -> U, 8..15 -> V)
    const int t  = threadIdx.x;
    const int m0 = bx * 64;
    const int half = by >> 3;                       // 0=U, 1=V
    const int n0   = (by & 7) * 64;
    const float* Bbase = W0 + half * (DIM_ * H0_);  // row offset 512 for V
    float* Cbase = ws + half * (NROWS * H0_);

    // Per-thread A-load address (row-major O, skip t=0)
    const int mload = m0 + (t >> 2);
    const int kload = (t & 3) * 4;
    {
    }
    const int b_  = mload / (TM1 * K_);
    const int rem = mload % (TM1 * K_);
    const int tt  = rem / K_;
    const int io  = rem % K_;
    const float* Arow = O + (((size_t)(b_ * T_ + tt + 1) * K_ + io) * DIM_);

    const int tm = t & 15, tn = t >> 4;
    float acc[4][4];
    #pragma unroll
    for (int r = 0; r < 4; ++r)
        #pragma unroll
        for (int c = 0; c < 4; ++c) acc[r][c] = 0.f;

    for (int k0 = 0; k0 < DIM_; k0 += 16) {
        // Stage A tile 64x16 (float4 along k, transposed store)
        float4 a4 = *(const float4*)(Arow + k0 + kload);
        As[kload + 0][t >> 2] = a4.x;
        As[kload + 1][t >> 2] = a4.y;
        As[kload + 2][t >> 2] = a4.z;
        As[kload + 3][t >> 2] = a4.w;
        // Stage B tile 16x64 (float4 along n)
        {
            const int kb = t >> 4;           // 0..15
            const int nb = (t & 15) * 4;     // 0..60
            float4 b4 = *(const float4*)(Bbase + (size_t)(k0 + kb) * H0_ + n0 + nb);
            *(float4*)&Bs[kb][nb] = b4;
        }
        __syncthreads();
        #pragma unroll
        for (int k = 0; k < 16; ++k) {
            float4 a = *(const float4*)&As[k][tm * 4];
            float4 w = *(const float4*)&Bs[k][tn * 4];
            const float av[4] = {a.x, a.y, a.z, a.w};
            const float wv[4] = {w.x, w.y, w.z, w.w};
            #pragma unroll
            for (int r = 0; r < 4; ++r)
                #pragma unroll
                for (int c = 0; c < 4; ++c)
                    acc[r][c] += av[r] * wv[c];
        }
        __syncthreads();
    }

    #pragma unroll
    for (int r = 0; r < 4; ++r) {
        float4 v = {acc[r][0], acc[r][1], acc[r][2], acc[r][3]};
        *(float4*)(Cbase + (size_t)(m0 + tm * 4 + r) * H0_ + n0 + tn * 4) = v;
    }
}

// ---------------------------------------------------------------------------
// Kernel 2: is_obj. One block per (b,t'): 16 row sums -> clip -> 256 products.
// ---------------------------------------------------------------------------
__global__ __launch_bounds__(256) void k_obj(const float* __restrict__ O,
                                             float* __restrict__ out)
{
    __shared__ float red[16][16];
    __shared__ float fl[16];
    const int bt = blockIdx.x;            // 0..351
    const int b_ = bt / TM1, tt = bt % TM1;
    const int t  = threadIdx.x;
    const int i  = t >> 4, s = t & 15;

    const float* base = O + (((size_t)(b_ * T_ + tt + 1) * K_ + i) * DIM_) + s * 32;
    float sum = 0.f;
    #pragma unroll
    for (int q = 0; q < 8; ++q) {
        float4 v = *(const float4*)(base + q * 4);
        sum += v.x + v.y + v.z + v.w;
    }
    red[i][s] = sum;
    __syncthreads();
    if (t < 16) {
        float f = 0.f;
        #pragma unroll
        for (int s2 = 0; s2 < 16; ++s2) f += red[t][s2];
        fl[t] = fminf(fmaxf(f, 0.f), 1.f);
    }
    __syncthreads();
    const float val = fminf((float)(tt + 1) * fl[t >> 4] * fl[t & 15], 1.f);
    out[(size_t)E_ELEMS + (size_t)bt * 256 + t] = val;
}

// ---------------------------------------------------------------------------
// Kernel 3: fused e = relu(relu(U_i + V_j + b0) @ W1 + b1).
// Block = one (b,t) x 64-pair tile x 128-col tile. 256 threads, 4x8 micro-tile.
// KC = 32: hs[32][64] (h tile, rebuilt from U,V,b0), wl[32][128] (W1 tile).
// ---------------------------------------------------------------------------
__global__ __launch_bounds__(256) void k_e(const float* __restrict__ U,
                                           const float* __restrict__ V,
                                           const float* __restrict__ b0,
                                           const float* __restrict__ W1,
                                           const float* __restrict__ b1,
                                           float* __restrict__ out)
{
    __shared__ alignas(16) float hs[32][64];
    __shared__ alignas(16) float wl[32][128];

    const int bid = blockIdx.x;          // 352*8 blocks
    const int bt  = bid >> 3;
    const int pt  = (bid >> 1) & 3;      // pair tile (64 pairs each)
    const int ct  = bid & 1;             // col tile (128 cols each)
    const int t   = threadIdx.x;

    const float* Ub = U + (size_t)(bt * K_ + pt * 4) * H0_;  // 4 rows used
    const float* Vb = V + (size_t)(bt * K_) * H0_;           // 16 rows used

    const int p     = t & 63;            // local pair for hs fill
    const int kg    = t >> 6;            // wave id 0..3
    const int i_loc = p >> 4;            // 0..3
    const int j_loc = p & 15;

    const int tp = t & 15;               // pair group (4 pairs)
    const int tn = t >> 4;               // col group (8 cols)

    float acc[4][8];
    #pragma unroll
    for (int r = 0; r < 4; ++r)
        #pragma unroll
        for (int c = 0; c < 8; ++c) acc[r][c] = 0.f;

    for (int k0 = 0; k0 < H0_; k0 += 32) {
        // Stage W1 tile 32x128
        #pragma unroll
        for (int r = 0; r < 4; ++r) {
            const int k  = r * 8 + (t >> 5);   // 0..31
            const int n4 = t & 31;             // 0..31
            *(float4*)&wl[k][n4 * 4] =
                *(const float4*)(W1 + (size_t)(k0 + k) * H1_ + ct * 128 + n4 * 4);
        }
        // Build h tile 32x64: relu(U_i + V_j + b0)
        #pragma unroll
        for (int kk = 0; kk < 8; ++kk) {
            const int k = kg * 8 + kk;         // uniform per wave
            const float u = Ub[(size_t)i_loc * H0_ + k0 + k];
            const float v = Vb[(size_t)j_loc * H0_ + k0 + k];
            hs[k][p] = relu_f(u + v + b0[k0 + k]);
        }
        __syncthreads();
        #pragma unroll
        for (int k = 0; k < 32; ++k) {
            float4 h4 = *(const float4*)&hs[k][tp * 4];
            float4 wA = *(const float4*)&wl[k][tn * 8];
            float4 wB = *(const float4*)&wl[k][tn * 8 + 4];
            const float hv[4] = {h4.x, h4.y, h4.z, h4.w};
            const float wv[8] = {wA.x, wA.y, wA.z, wA.w, wB.x, wB.y, wB.z, wB.w};
            #pragma unroll
            for (int r = 0; r < 4; ++r)
                #pragma unroll
                for (int c = 0; c < 8; ++c)
                    acc[r][c] += hv[r] * wv[c];
        }
        __syncthreads();
    }

    // Epilogue: + b1, relu, store
    float bb[8];
    #pragma unroll
    for (int c = 0; c < 8; ++c) bb[c] = b1[ct * 128 + tn * 8 + c];
    float* ob = out + (size_t)bt * (256 * H1_) + (size_t)(pt * 64 + tp * 4) * H1_ + ct * 128 + tn * 8;
    #pragma unroll
    for (int r = 0; r < 4; ++r) {
        float4 v0, v1;
        v0.x = relu_f(acc[r][0] + bb[0]);
        v0.y = relu_f(acc[r][1] + bb[1]);
        v0.z = relu_f(acc[r][2] + bb[2]);
        v0.w = relu_f(acc[r][3] + bb[3]);
        v1.x = relu_f(acc[r][4] + bb[4]);
        v1.y = relu_f(acc[r][5] + bb[5]);
        v1.z = relu_f(acc[r][6] + bb[6]);
        v1.w = relu_f(acc[r][7] + bb[7]);
        *(float4*)(ob + (size_t)r * H1_)     = v0;
        *(float4*)(ob + (size_t)r * H1_ + 4) = v1;
    }
}

// ---------------------------------------------------------------------------
extern "C" void kernel_launch(void* const* d_in, const int* in_sizes, int n_in,
                              void* d_out, int out_size, void* d_ws, size_t ws_size,
                              hipStream_t stream) {
    const float* O  = (const float*)d_in[0];   // (32,12,16,512)
    const float* W0 = (const float*)d_in[1];   // (1024,512)
    const float* b0 = (const float*)d_in[2];   // (512)
    const float* W1 = (const float*)d_in[3];   // (512,256)
    const float* b1 = (const float*)d_in[4];   // (256)
    float* out = (float*)d_out;

    float* U = (float*)d_ws;                   // [5632][512]
    float* V = U + (size_t)NROWS * H0_;        // [5632][512]  (needs 23,068,672 B of ws)

    dim3 g1(88, 16);
    k_uv<<<g1, 256, 0, stream>>>(O, W0, (float*)d_ws);
    k_obj<<<NBT, 256, 0, stream>>>(O, out);
    k_e<<<NBT * 8, 256, 0, stream>>>(U, V, b0, W1, b1, out);
}

// Round 3
// 113.376 us; speedup vs baseline: 3.2395x; 3.2395x over previous
//
#include <hip/hip_runtime.h>
#include <hip/hip_bf16.h>

#define B_    32
#define T_    12
#define TM1   11
#define K_    16
#define DIM_  512
#define H0_   512
#define H1_   256
#define NROWS 5632          // B_*TM1*K_
#define NBT   352           // B_*TM1
#define E_ELEMS (NBT*256*H1_)   // 23,068,672

typedef __bf16 bf16x8 __attribute__((ext_vector_type(8)));
typedef float  f32x16 __attribute__((ext_vector_type(16)));
typedef unsigned u32x4 __attribute__((ext_vector_type(4)));

// ws layout (bytes):
//  Ofrag : [32 s][176 mt][64 lane][16B]        = 5,767,168
//  W0frag: [2 half][32 s][16 nt][64][16B]      = 1,048,576
//  W1frag: [32 s][8 ct][64][16B]               =   262,144
//  Ub    : bf16 [5632][512]  (U + b0 folded)   = 5,767,168
//  Vsw   : bf16 [352][16][512] chunk-XOR sw    = 5,767,168
#define OFRAG_OFF   0
#define W0FRAG_OFF  5767168
#define W1FRAG_OFF  (W0FRAG_OFF + 1048576)
#define UB_OFF      (W1FRAG_OFF + 262144)
#define VSW_OFF     (UB_OFF + 5767168)
// total = 18,612,224 B  (< 23,068,672 available)

// RNE fp32->bf16 via bit ops (matches __float2bfloat16_rn for finite values)
__device__ __forceinline__ unsigned bf_rn(float f) {
    unsigned u = __float_as_uint(f);
    return (u + 0x7fffu + ((u >> 16) & 1u)) >> 16;
}
__device__ __forceinline__ unsigned pk_bf16(float lo, float hi) {
    return bf_rn(lo) | (bf_rn(hi) << 16);
}
__device__ __forceinline__ unsigned short f2bf(float f) {
    return (unsigned short)bf_rn(f);
}
__device__ __forceinline__ float bfu_lo(unsigned u) { return __uint_as_float(u << 16); }
__device__ __forceinline__ float bfu_hi(unsigned u) { return __uint_as_float(u & 0xffff0000u); }

// ---------------------------------------------------------------------------
// Prep: W0 -> W0frag, W1 -> W1frag (fragment-ordered bf16).
// frag element [s][nt][lane][j] = W[k = s*16 + (lane>>5)*8 + j][n = nt*32 + (lane&31)]
// ---------------------------------------------------------------------------
__global__ __launch_bounds__(64) void k_prep_w(const float* __restrict__ W0,
                                               const float* __restrict__ W1,
                                               char* __restrict__ ws)
{
    const int bid = blockIdx.x, l = threadIdx.x;
    const float* src; size_t dstoff; int stride;
    if (bid < 1024) {
        int half = bid >> 9, s = (bid >> 4) & 31, nt = bid & 15;
        int k = s*16 + (l >> 5)*8;
        int n = nt*32 + (l & 31);
        src = W0 + (size_t)(half*512 + k) * H0_ + n;
        stride = H0_;
        dstoff = W0FRAG_OFF + (((size_t)(half*32 + s)*16 + nt)*64 + l)*16;
    } else {
        int r = bid - 1024; int s = r >> 3, ct = r & 7;
        int k = s*16 + (l >> 5)*8;
        int n = ct*32 + (l & 31);
        src = W1 + (size_t)k * H1_ + n;
        stride = H1_;
        dstoff = W1FRAG_OFF + (((size_t)(s*8 + ct))*64 + l)*16;
    }
    float f[8];
    #pragma unroll
    for (int j = 0; j < 8; ++j) f[j] = src[(size_t)j * stride];
    u32x4 o = { pk_bf16(f[0],f[1]), pk_bf16(f[2],f[3]), pk_bf16(f[4],f[5]), pk_bf16(f[6],f[7]) };
    *(u32x4*)(ws + dstoff) = o;
}

// ---------------------------------------------------------------------------
// Prep: O_t -> Ofrag bf16. row = mt*32 + (lane&31) over (b,t',i); k as above.
// ---------------------------------------------------------------------------
__global__ __launch_bounds__(64) void k_prep_o(const float* __restrict__ O,
                                               char* __restrict__ ws)
{
    const int bid = blockIdx.x;                 // s*176 + mt
    const int s = bid / 176, mt = bid % 176, l = threadIdx.x;
    const int row = mt*32 + (l & 31);
    const int b  = row / (TM1*K_);
    const int rem = row % (TM1*K_);
    const int t  = rem / K_;
    const int i  = rem % K_;
    const float* src = O + (((size_t)(b*T_ + t + 1)*K_ + i)*DIM_) + s*16 + (l >> 5)*8;
    float4 a = *(const float4*)src;
    float4 c = *(const float4*)(src + 4);
    u32x4 o = { pk_bf16(a.x,a.y), pk_bf16(a.z,a.w), pk_bf16(c.x,c.y), pk_bf16(c.z,c.w) };
    *(u32x4*)(ws + OFRAG_OFF + ((size_t)(s*176 + mt)*64 + l)*16) = o;
}

// ---------------------------------------------------------------------------
// k_uv: [5632 x 512] @ [512 x 1024] -> Ub (bf16, +b0) / Vsw (bf16, chunk-XOR)
// Block 128x128, 4 waves (2x2), wave 64x64 = 2x2 MFMA 32x32x16 tiles.
// ---------------------------------------------------------------------------
__global__ __launch_bounds__(256) void k_uv(char* __restrict__ ws,
                                            const float* __restrict__ b0)
{
    __shared__ alignas(16) char lds[16384];   // A dbuf 2x4KB @0, B dbuf 2x4KB @8192
    const int bid = blockIdx.x;               // mb*8 + nb
    const int mb = bid >> 3, nb = bid & 7;
    const int t = threadIdx.x, l = t & 63, w = t >> 6;
    const int wr = w & 1, wc = w >> 1;
    const int half = nb >> 2;
    const char* Aglob = ws + OFRAG_OFF;
    const char* Bglob = ws + W0FRAG_OFF + (size_t)half * 524288;
    const int nt0 = (nb & 3) * 4;

    f32x16 acc[2][2];
    #pragma unroll
    for (int p = 0; p < 2; ++p)
        #pragma unroll
        for (int c = 0; c < 2; ++c)
            #pragma unroll
            for (int r = 0; r < 16; ++r) acc[p][c][r] = 0.f;

    // stage s=0
    {
        u32x4 av = *(const u32x4*)(Aglob + ((size_t)(0*176 + mb*4))*1024 + t*16);
        u32x4 bv = *(const u32x4*)(Bglob + ((size_t)(0*16 + nt0))*1024 + t*16);
        *(u32x4*)(lds + t*16) = av;
        *(u32x4*)(lds + 8192 + t*16) = bv;
    }
    __syncthreads();

    for (int s = 0; s < 32; ++s) {
        const int cur = s & 1;
        if (s < 31) {
            u32x4 av = *(const u32x4*)(Aglob + ((size_t)((s+1)*176 + mb*4))*1024 + t*16);
            u32x4 bv = *(const u32x4*)(Bglob + ((size_t)((s+1)*16 + nt0))*1024 + t*16);
            *(u32x4*)(lds + (cur^1)*4096 + t*16) = av;
            *(u32x4*)(lds + 8192 + (cur^1)*4096 + t*16) = bv;
        }
        bf16x8 a0 = *(const bf16x8*)(lds + cur*4096 + (wr*2+0)*1024 + l*16);
        bf16x8 a1 = *(const bf16x8*)(lds + cur*4096 + (wr*2+1)*1024 + l*16);
        bf16x8 bb0 = *(const bf16x8*)(lds + 8192 + cur*4096 + (wc*2+0)*1024 + l*16);
        bf16x8 bb1 = *(const bf16x8*)(lds + 8192 + cur*4096 + (wc*2+1)*1024 + l*16);
        acc[0][0] = __builtin_amdgcn_mfma_f32_32x32x16_bf16(a0, bb0, acc[0][0], 0, 0, 0);
        acc[0][1] = __builtin_amdgcn_mfma_f32_32x32x16_bf16(a0, bb1, acc[0][1], 0, 0, 0);
        acc[1][0] = __builtin_amdgcn_mfma_f32_32x32x16_bf16(a1, bb0, acc[1][0], 0, 0, 0);
        acc[1][1] = __builtin_amdgcn_mfma_f32_32x32x16_bf16(a1, bb1, acc[1][1], 0, 0, 0);
        __syncthreads();
    }

    // Epilogue: C layout col = l&31, row = (r&3) + 8*(r>>2) + 4*(l>>5)  [m101]
    #pragma unroll
    for (int am = 0; am < 2; ++am) {
        #pragma unroll
        for (int bn = 0; bn < 2; ++bn) {
            const int col = (nb & 3)*128 + wc*64 + bn*32 + (l & 31);
            const float bias = (half == 0) ? b0[col] : 0.f;
            #pragma unroll
            for (int r = 0; r < 16; ++r) {
                const int row = (r & 3) + 8*(r >> 2) + 4*(l >> 5);
                const int M = mb*128 + wr*64 + am*32 + row;
                const float v = acc[am][bn][r] + bias;
                if (half == 0) {
                    *(unsigned short*)(ws + UB_OFF + ((size_t)M*512 + col)*2) = f2bf(v);
                } else {
                    const int bt = M >> 4, j = M & 15;
                    const int cc = col >> 3;
                    const int c2 = ((cc ^ (j & 7)) << 3) | (col & 7);
                    *(unsigned short*)(ws + VSW_OFF + ((size_t)(bt*16 + j)*512 + c2)*2) = f2bf(v);
                }
            }
        }
    }
}

// ---------------------------------------------------------------------------
// k_obj: is_obj output (unchanged — correct & cheap).
// ---------------------------------------------------------------------------
__global__ __launch_bounds__(256) void k_obj(const float* __restrict__ O,
                                             float* __restrict__ out)
{
    __shared__ float red[16][16];
    __shared__ float fl[16];
    const int bt = blockIdx.x;
    const int b_ = bt / TM1, tt = bt % TM1;
    const int t  = threadIdx.x;
    const int i  = t >> 4, s = t & 15;
    const float* base = O + (((size_t)(b_ * T_ + tt + 1) * K_ + i) * DIM_) + s * 32;
    float sum = 0.f;
    #pragma unroll
    for (int q = 0; q < 8; ++q) {
        float4 v = *(const float4*)(base + q * 4);
        sum += v.x + v.y + v.z + v.w;
    }
    red[i][s] = sum;
    __syncthreads();
    if (t < 16) {
        float f = 0.f;
        #pragma unroll
        for (int s2 = 0; s2 < 16; ++s2) f += red[t][s2];
        fl[t] = fminf(fmaxf(f, 0.f), 1.f);
    }
    __syncthreads();
    const float val = fminf((float)(tt + 1) * fl[t >> 4] * fl[t & 15], 1.f);
    out[(size_t)E_ELEMS + (size_t)bt * 256 + t] = val;
}

// ---------------------------------------------------------------------------
// k_e: e = relu( relu(U_i + V_j) @ W1 + b1 ), A-frags built in registers.
// Block = (bt, pairhalf): 128 pairs x 256 cols. 4 waves (wp,wc), wave 64x128.
// ---------------------------------------------------------------------------
__global__ __launch_bounds__(256, 2) void k_e(const char* __restrict__ ws,
                                              const float* __restrict__ b1,
                                              float* __restrict__ out)
{
    __shared__ alignas(16) char lds[8192 + 16384 + 16384];
    char* Us = lds;                 // [8][512] bf16
    char* Vs = lds + 8192;          // [16][512] bf16 (chunk-XOR content)
    char* Wb = lds + 24576;         // double buffer 2 x [8 ct][64][16B]

    const int bid = blockIdx.x;     // bt*2 + ph
    const int bt = bid >> 1, ph = bid & 1;
    const int t = threadIdx.x, l = t & 63, w = t >> 6;
    const int wp = w & 1, wc = w >> 1;

    const char* Ug = ws + UB_OFF  + (size_t)(bt*16 + ph*8) * 1024;  // 8 KB
    const char* Vg = ws + VSW_OFF + (size_t)bt * 16384;             // 16 KB
    const char* Wg = ws + W1FRAG_OFF;                                // [32 s][8 KB]

    // one-time staging (linear copies)
    #pragma unroll
    for (int r = 0; r < 2; ++r) { int c = t + r*256; *(u32x4*)(Us + c*16) = *(const u32x4*)(Ug + c*16); }
    #pragma unroll
    for (int r = 0; r < 4; ++r) { int c = t + r*256; *(u32x4*)(Vs + c*16) = *(const u32x4*)(Vg + c*16); }
    #pragma unroll
    for (int r = 0; r < 2; ++r) { int c = t + r*256; *(u32x4*)(Wb + c*16) = *(const u32x4*)(Wg + c*16); }
    __syncthreads();

    f32x16 acc[2][4];
    #pragma unroll
    for (int p = 0; p < 2; ++p)
        #pragma unroll
        for (int c = 0; c < 4; ++c)
            #pragma unroll
            for (int r = 0; r < 16; ++r) acc[p][c][r] = 0.f;

    const int jj = l & 15;
    const int kc = l >> 5;
    const int ih = (l >> 4) & 1;

    for (int s = 0; s < 32; ++s) {
        const int cur = s & 1;
        if (s < 31) {
            #pragma unroll
            for (int r = 0; r < 2; ++r) {
                int c = t + r*256;
                *(u32x4*)(Wb + (cur^1)*8192 + c*16) =
                    *(const u32x4*)(Wg + (size_t)(s+1)*8192 + c*16);
            }
        }
        // V fragment source (swizzled chunk)
        const int vchunk = (s*2 + kc) ^ (jj & 7);
        u32x4 vu = *(const u32x4*)(Vs + jj*1024 + vchunk*16);
        float vf[8];
        #pragma unroll
        for (int q = 0; q < 4; ++q) { vf[2*q] = bfu_lo(vu[q]); vf[2*q+1] = bfu_hi(vu[q]); }

        bf16x8 afrag[2];
        #pragma unroll
        for (int p = 0; p < 2; ++p) {
            const int iloc = wp*4 + p*2 + ih;
            u32x4 uu = *(const u32x4*)(Us + iloc*1024 + s*32 + kc*16);
            u32x4 o;
            #pragma unroll
            for (int q = 0; q < 4; ++q) {
                float h0 = fmaxf(bfu_lo(uu[q]) + vf[2*q],   0.f);
                float h1 = fmaxf(bfu_hi(uu[q]) + vf[2*q+1], 0.f);
                o[q] = pk_bf16(h0, h1);
            }
            union { u32x4 u; bf16x8 b; } cv; cv.u = o;
            afrag[p] = cv.b;
        }

        bf16x8 bfr[4];
        #pragma unroll
        for (int c = 0; c < 4; ++c)
            bfr[c] = *(const bf16x8*)(Wb + cur*8192 + (wc*4 + c)*1024 + l*16);

        #pragma unroll
        for (int p = 0; p < 2; ++p)
            #pragma unroll
            for (int c = 0; c < 4; ++c)
                acc[p][c] = __builtin_amdgcn_mfma_f32_32x32x16_bf16(afrag[p], bfr[c], acc[p][c], 0, 0, 0);
        __syncthreads();
    }

    // epilogue: + b1, relu, store fp32
    #pragma unroll
    for (int c = 0; c < 4; ++c) {
        const int col = wc*128 + c*32 + (l & 31);
        const float bb = b1[col];
        #pragma unroll
        for (int p = 0; p < 2; ++p) {
            #pragma unroll
            for (int r = 0; r < 16; ++r) {
                const int pair = ph*128 + wp*64 + p*32 + (r & 3) + 8*(r >> 2) + 4*(l >> 5);
                const float v = fmaxf(acc[p][c][r] + bb, 0.f);
                out[((size_t)bt*256 + pair)*256 + col] = v;
            }
        }
    }
}

// ---------------------------------------------------------------------------
extern "C" void kernel_launch(void* const* d_in, const int* in_sizes, int n_in,
                              void* d_out, int out_size, void* d_ws, size_t ws_size,
                              hipStream_t stream) {
    const float* O  = (const float*)d_in[0];
    const float* W0 = (const float*)d_in[1];
    const float* b0 = (const float*)d_in[2];
    const float* W1 = (const float*)d_in[3];
    const float* b1 = (const float*)d_in[4];
    float* out = (float*)d_out;
    char* ws = (char*)d_ws;

    k_prep_w<<<1280, 64, 0, stream>>>(W0, W1, ws);
    k_prep_o<<<5632, 64, 0, stream>>>(O, ws);
    k_uv<<<352, 256, 0, stream>>>(ws, b0);
    k_obj<<<NBT, 256, 0, stream>>>(O, out);
    k_e<<<NBT * 2, 256, 0, stream>>>(ws, b1, out);
}

// Round 4
// 84.090 us; speedup vs baseline: 4.3677x; 1.3483x over previous
//
#include <hip/hip_runtime.h>
#include <hip/hip_bf16.h>

#define B_    32
#define T_    12
#define TM1   11
#define K_    16
#define DIM_  512
#define H0_   512
#define H1_   256
#define NROWS 5632          // B_*TM1*K_
#define NBT   352           // B_*TM1
#define E_ELEMS (NBT*256*H1_)   // 23,068,672

typedef __bf16 bf16x8 __attribute__((ext_vector_type(8)));
typedef float  f32x16 __attribute__((ext_vector_type(16)));
typedef unsigned u32x4 __attribute__((ext_vector_type(4)));

// ws layout (bytes):
//  Ofrag : [32 s][176 mt][64 lane][16B]        = 5,767,168
//  W0frag: [2 half][32 s][16 nt][64][16B]      = 1,048,576
//  W1frag: [32 s][8 ct][64][16B]               =   262,144
//  Ub    : bf16 [5632][512]  (U + b0 folded)   = 5,767,168
//  Vsw   : bf16 [352][16][512] chunk-XOR sw    = 5,767,168
#define OFRAG_OFF   0
#define W0FRAG_OFF  5767168
#define W1FRAG_OFF  (W0FRAG_OFF + 1048576)
#define UB_OFF      (W1FRAG_OFF + 262144)
#define VSW_OFF     (UB_OFF + 5767168)
// total = 18,612,224 B

// RNE fp32->bf16 via bit ops (matches RNE for finite values)
__device__ __forceinline__ unsigned bf_rn(float f) {
    unsigned u = __float_as_uint(f);
    return (u + 0x7fffu + ((u >> 16) & 1u)) >> 16;
}
__device__ __forceinline__ unsigned pk_bf16(float lo, float hi) {
    return bf_rn(lo) | (bf_rn(hi) << 16);
}
__device__ __forceinline__ unsigned short f2bf(float f) {
    return (unsigned short)bf_rn(f);
}
__device__ __forceinline__ float bfu_lo(unsigned u) { return __uint_as_float(u << 16); }
__device__ __forceinline__ float bfu_hi(unsigned u) { return __uint_as_float(u & 0xffff0000u); }
// HW packed convert: dst = bf16(lo) | bf16(hi)<<16, RNE (no builtin on gfx950)
__device__ __forceinline__ unsigned cvt_pk(float lo, float hi) {
    unsigned r;
    asm("v_cvt_pk_bf16_f32 %0, %1, %2" : "=v"(r) : "v"(lo), "v"(hi));
    return r;
}

// ---------------------------------------------------------------------------
// Prep: W0 -> W0frag, W1 -> W1frag (fragment-ordered bf16).
// frag element [s][nt][lane][j] = W[k = s*16 + (lane>>5)*8 + j][n = nt*32 + (lane&31)]
// ---------------------------------------------------------------------------
__global__ __launch_bounds__(64) void k_prep_w(const float* __restrict__ W0,
                                               const float* __restrict__ W1,
                                               char* __restrict__ ws)
{
    const int bid = blockIdx.x, l = threadIdx.x;
    const float* src; size_t dstoff; int stride;
    if (bid < 1024) {
        int half = bid >> 9, s = (bid >> 4) & 31, nt = bid & 15;
        int k = s*16 + (l >> 5)*8;
        int n = nt*32 + (l & 31);
        src = W0 + (size_t)(half*512 + k) * H0_ + n;
        stride = H0_;
        dstoff = W0FRAG_OFF + (((size_t)(half*32 + s)*16 + nt)*64 + l)*16;
    } else {
        int r = bid - 1024; int s = r >> 3, ct = r & 7;
        int k = s*16 + (l >> 5)*8;
        int n = ct*32 + (l & 31);
        src = W1 + (size_t)k * H1_ + n;
        stride = H1_;
        dstoff = W1FRAG_OFF + (((size_t)(s*8 + ct))*64 + l)*16;
    }
    float f[8];
    #pragma unroll
    for (int j = 0; j < 8; ++j) f[j] = src[(size_t)j * stride];
    u32x4 o = { pk_bf16(f[0],f[1]), pk_bf16(f[2],f[3]), pk_bf16(f[4],f[5]), pk_bf16(f[6],f[7]) };
    *(u32x4*)(ws + dstoff) = o;
}

// ---------------------------------------------------------------------------
// Prep: O_t -> Ofrag bf16. row = mt*32 + (lane&31) over (b,t',i); k as above.
// ---------------------------------------------------------------------------
__global__ __launch_bounds__(64) void k_prep_o(const float* __restrict__ O,
                                               char* __restrict__ ws)
{
    const int bid = blockIdx.x;                 // s*176 + mt
    const int s = bid / 176, mt = bid % 176, l = threadIdx.x;
    const int row = mt*32 + (l & 31);
    const int b  = row / (TM1*K_);
    const int rem = row % (TM1*K_);
    const int t  = rem / K_;
    const int i  = rem % K_;
    const float* src = O + (((size_t)(b*T_ + t + 1)*K_ + i)*DIM_) + s*16 + (l >> 5)*8;
    float4 a = *(const float4*)src;
    float4 c = *(const float4*)(src + 4);
    u32x4 o = { pk_bf16(a.x,a.y), pk_bf16(a.z,a.w), pk_bf16(c.x,c.y), pk_bf16(c.z,c.w) };
    *(u32x4*)(ws + OFRAG_OFF + ((size_t)(s*176 + mt)*64 + l)*16) = o;
}

// ---------------------------------------------------------------------------
// k_uv: [5632 x 512] @ [512 x 1024] -> Ub (bf16, +b0) / Vsw (bf16, chunk-XOR)
// 1 wave per block, 64x64 tile, NO LDS, NO barriers, 2-step register prefetch.
// Fragments read directly from Ofrag / W0frag (L2-resident).
// ---------------------------------------------------------------------------
__global__ __launch_bounds__(64) void k_uv(char* __restrict__ ws,
                                           const float* __restrict__ b0)
{
    const int mb = blockIdx.x;     // 0..87  (64-row strip)
    const int nb = blockIdx.y;     // 0..15  (64-col strip over 1024)
    const int l  = threadIdx.x;
    const int half = nb >> 3;
    const char* Ag = ws + OFRAG_OFF + ((size_t)(mb*2)*64 + l)*16;
    const char* Bg = ws + W0FRAG_OFF + (size_t)half*524288 + ((size_t)((nb&7)*2)*64 + l)*16;
    // step strides (bytes)
    const size_t AS = 176*1024, BS = 16*1024;

    f32x16 acc[2][2];
    #pragma unroll
    for (int p = 0; p < 2; ++p)
        #pragma unroll
        for (int c = 0; c < 2; ++c)
            #pragma unroll
            for (int r = 0; r < 16; ++r) acc[p][c][r] = 0.f;

    u32x4 aA[2], bA[2], aB[2], bB[2];
    #pragma unroll
    for (int p = 0; p < 2; ++p) {
        aA[p] = *(const u32x4*)(Ag + 0*AS + p*1024);
        bA[p] = *(const u32x4*)(Bg + 0*BS + p*1024);
        aB[p] = *(const u32x4*)(Ag + 1*AS + p*1024);
        bB[p] = *(const u32x4*)(Bg + 1*BS + p*1024);
    }

    for (int ss = 0; ss < 32; ss += 2) {
        // body 0: compute with aA/bA, prefetch ss+2
        {
            union { u32x4 u[2]; bf16x8 b[2]; } af, bf;
            af.u[0]=aA[0]; af.u[1]=aA[1]; bf.u[0]=bA[0]; bf.u[1]=bA[1];
            if (ss + 2 < 32) {
                #pragma unroll
                for (int p = 0; p < 2; ++p) {
                    aA[p] = *(const u32x4*)(Ag + (size_t)(ss+2)*AS + p*1024);
                    bA[p] = *(const u32x4*)(Bg + (size_t)(ss+2)*BS + p*1024);
                }
            }
            acc[0][0] = __builtin_amdgcn_mfma_f32_32x32x16_bf16(af.b[0], bf.b[0], acc[0][0], 0,0,0);
            acc[0][1] = __builtin_amdgcn_mfma_f32_32x32x16_bf16(af.b[0], bf.b[1], acc[0][1], 0,0,0);
            acc[1][0] = __builtin_amdgcn_mfma_f32_32x32x16_bf16(af.b[1], bf.b[0], acc[1][0], 0,0,0);
            acc[1][1] = __builtin_amdgcn_mfma_f32_32x32x16_bf16(af.b[1], bf.b[1], acc[1][1], 0,0,0);
        }
        // body 1: compute with aB/bB, prefetch ss+3
        {
            union { u32x4 u[2]; bf16x8 b[2]; } af, bf;
            af.u[0]=aB[0]; af.u[1]=aB[1]; bf.u[0]=bB[0]; bf.u[1]=bB[1];
            if (ss + 3 < 32) {
                #pragma unroll
                for (int p = 0; p < 2; ++p) {
                    aB[p] = *(const u32x4*)(Ag + (size_t)(ss+3)*AS + p*1024);
                    bB[p] = *(const u32x4*)(Bg + (size_t)(ss+3)*BS + p*1024);
                }
            }
            acc[0][0] = __builtin_amdgcn_mfma_f32_32x32x16_bf16(af.b[0], bf.b[0], acc[0][0], 0,0,0);
            acc[0][1] = __builtin_amdgcn_mfma_f32_32x32x16_bf16(af.b[0], bf.b[1], acc[0][1], 0,0,0);
            acc[1][0] = __builtin_amdgcn_mfma_f32_32x32x16_bf16(af.b[1], bf.b[0], acc[1][0], 0,0,0);
            acc[1][1] = __builtin_amdgcn_mfma_f32_32x32x16_bf16(af.b[1], bf.b[1], acc[1][1], 0,0,0);
        }
    }

    // Epilogue: C layout col = l&31, row = (r&3) + 8*(r>>2) + 4*(l>>5)  [m101]
    #pragma unroll
    for (int p = 0; p < 2; ++p) {
        #pragma unroll
        for (int c = 0; c < 2; ++c) {
            const int col = (nb & 7)*64 + c*32 + (l & 31);   // within 512-wide half
            const float bias = (half == 0) ? b0[col] : 0.f;
            #pragma unroll
            for (int r = 0; r < 16; ++r) {
                const int row = (r & 3) + 8*(r >> 2) + 4*(l >> 5);
                const int M = mb*64 + p*32 + row;
                const float v = acc[p][c][r] + bias;
                if (half == 0) {
                    *(unsigned short*)(ws + UB_OFF + ((size_t)M*512 + col)*2) = f2bf(v);
                } else {
                    const int bt = M >> 4, j = M & 15;
                    const int cc = col >> 3;
                    const int c2 = ((cc ^ (j & 7)) << 3) | (col & 7);
                    *(unsigned short*)(ws + VSW_OFF + ((size_t)(bt*16 + j)*512 + c2)*2) = f2bf(v);
                }
            }
        }
    }
}

// ---------------------------------------------------------------------------
// k_obj: is_obj output (unchanged — correct & cheap).
// ---------------------------------------------------------------------------
__global__ __launch_bounds__(256) void k_obj(const float* __restrict__ O,
                                             float* __restrict__ out)
{
    __shared__ float red[16][16];
    __shared__ float fl[16];
    const int bt = blockIdx.x;
    const int b_ = bt / TM1, tt = bt % TM1;
    const int t  = threadIdx.x;
    const int i  = t >> 4, s = t & 15;
    const float* base = O + (((size_t)(b_ * T_ + tt + 1) * K_ + i) * DIM_) + s * 32;
    float sum = 0.f;
    #pragma unroll
    for (int q = 0; q < 8; ++q) {
        float4 v = *(const float4*)(base + q * 4);
        sum += v.x + v.y + v.z + v.w;
    }
    red[i][s] = sum;
    __syncthreads();
    if (t < 16) {
        float f = 0.f;
        #pragma unroll
        for (int s2 = 0; s2 < 16; ++s2) f += red[t][s2];
        fl[t] = fminf(fmaxf(f, 0.f), 1.f);
    }
    __syncthreads();
    const float val = fminf((float)(tt + 1) * fl[t >> 4] * fl[t & 15], 1.f);
    out[(size_t)E_ELEMS + (size_t)bt * 256 + t] = val;
}

// ---------------------------------------------------------------------------
// k_e: e = relu( relu(U_i + V_j) @ W1 + b1 ). Barrier-free main loop:
// U,V staged to LDS once; W1 fragments read direct from global (L2-hot),
// software-pipelined 1 step; A-frags built in registers with v_cvt_pk_bf16_f32.
// Block = (bt, ph): 128 pairs x 256 cols, 4 waves (wp,wc), wave 64x128.
// ---------------------------------------------------------------------------
__global__ __launch_bounds__(256, 2) void k_e(const char* __restrict__ ws,
                                              const float* __restrict__ b1,
                                              float* __restrict__ out)
{
    __shared__ alignas(16) char lds[24576];
    char* Us = lds;                 // [8][512] bf16
    char* Vs = lds + 8192;          // [16][512] bf16 (chunk-XOR content)

    const int bid = blockIdx.x;     // bt*2 + ph
    const int bt = bid >> 1, ph = bid & 1;
    const int t = threadIdx.x, l = t & 63, w = t >> 6;
    const int wp = w & 1, wc = w >> 1;

    const char* Ug = ws + UB_OFF  + (size_t)(bt*16 + ph*8) * 1024;  // 8 KB
    const char* Vg = ws + VSW_OFF + (size_t)bt * 16384;             // 16 KB
    const char* Wg = ws + W1FRAG_OFF + (size_t)(wc*4)*1024 + (size_t)l*16; // per-lane

    // one-time staging (linear copies)
    #pragma unroll
    for (int r = 0; r < 2; ++r) { int c = t + r*256; *(u32x4*)(Us + c*16) = *(const u32x4*)(Ug + c*16); }
    #pragma unroll
    for (int r = 0; r < 4; ++r) { int c = t + r*256; *(u32x4*)(Vs + c*16) = *(const u32x4*)(Vg + c*16); }
    __syncthreads();

    f32x16 acc[2][4];
    #pragma unroll
    for (int p = 0; p < 2; ++p)
        #pragma unroll
        for (int c = 0; c < 4; ++c)
            #pragma unroll
            for (int r = 0; r < 16; ++r) acc[p][c][r] = 0.f;

    const int jj = l & 15;
    const int kc = l >> 5;
    const int ih = (l >> 4) & 1;

    // W1 register pipeline, depth 1
    u32x4 wn[4];
    #pragma unroll
    for (int c = 0; c < 4; ++c) wn[c] = *(const u32x4*)(Wg + c*1024);

    #pragma unroll 4
    for (int s = 0; s < 32; ++s) {
        union { u32x4 u[4]; bf16x8 b[4]; } wcur;
        #pragma unroll
        for (int c = 0; c < 4; ++c) wcur.u[c] = wn[c];
        if (s < 31) {
            #pragma unroll
            for (int c = 0; c < 4; ++c)
                wn[c] = *(const u32x4*)(Wg + (size_t)(s+1)*8192 + c*1024);
        }

        // V fragment (swizzled chunk), unpack to f32
        const int vchunk = (s*2 + kc) ^ (jj & 7);
        u32x4 vu = *(const u32x4*)(Vs + jj*1024 + vchunk*16);
        float vf[8];
        #pragma unroll
        for (int q = 0; q < 4; ++q) { vf[2*q] = bfu_lo(vu[q]); vf[2*q+1] = bfu_hi(vu[q]); }

        bf16x8 afrag[2];
        #pragma unroll
        for (int p = 0; p < 2; ++p) {
            const int iloc = wp*4 + p*2 + ih;
            u32x4 uu = *(const u32x4*)(Us + iloc*1024 + s*32 + kc*16);
            u32x4 o;
            #pragma unroll
            for (int q = 0; q < 4; ++q) {
                float h0 = fmaxf(bfu_lo(uu[q]) + vf[2*q],   0.f);
                float h1 = fmaxf(bfu_hi(uu[q]) + vf[2*q+1], 0.f);
                o[q] = cvt_pk(h0, h1);
            }
            union { u32x4 u; bf16x8 b; } cv; cv.u = o;
            afrag[p] = cv.b;
        }

        #pragma unroll
        for (int p = 0; p < 2; ++p)
            #pragma unroll
            for (int c = 0; c < 4; ++c)
                acc[p][c] = __builtin_amdgcn_mfma_f32_32x32x16_bf16(afrag[p], wcur.b[c], acc[p][c], 0, 0, 0);
    }

    // epilogue: + b1, relu, store fp32
    #pragma unroll
    for (int c = 0; c < 4; ++c) {
        const int col = wc*128 + c*32 + (l & 31);
        const float bb = b1[col];
        #pragma unroll
        for (int p = 0; p < 2; ++p) {
            #pragma unroll
            for (int r = 0; r < 16; ++r) {
                const int pair = ph*128 + wp*64 + p*32 + (r & 3) + 8*(r >> 2) + 4*(l >> 5);
                const float v = fmaxf(acc[p][c][r] + bb, 0.f);
                out[((size_t)bt*256 + pair)*256 + col] = v;
            }
        }
    }
}

// ---------------------------------------------------------------------------
extern "C" void kernel_launch(void* const* d_in, const int* in_sizes, int n_in,
                              void* d_out, int out_size, void* d_ws, size_t ws_size,
                              hipStream_t stream) {
    const float* O  = (const float*)d_in[0];
    const float* W0 = (const float*)d_in[1];
    const float* b0 = (const float*)d_in[2];
    const float* W1 = (const float*)d_in[3];
    const float* b1 = (const float*)d_in[4];
    float* out = (float*)d_out;
    char* ws = (char*)d_ws;

    k_prep_w<<<1280, 64, 0, stream>>>(W0, W1, ws);
    k_prep_o<<<5632, 64, 0, stream>>>(O, ws);
    dim3 guv(88, 16);
    k_uv<<<guv, 64, 0, stream>>>(ws, b0);
    k_obj<<<NBT, 256, 0, stream>>>(O, out);
    k_e<<<NBT * 2, 256, 0, stream>>>(ws, b1, out);
}

// Round 5
// 67.853 us; speedup vs baseline: 5.4129x; 1.2393x over previous
//
#include <hip/hip_runtime.h>
#include <hip/hip_bf16.h>

#define B_    32
#define T_    12
#define TM1   11
#define K_    16
#define DIM_  512
#define H0_   512
#define H1_   256
#define NROWS 5632          // B_*TM1*K_
#define NBT   352           // B_*TM1
#define E_ELEMS (NBT*256*H1_)   // 23,068,672

typedef __bf16 bf16x8 __attribute__((ext_vector_type(8)));
typedef float  f32x16 __attribute__((ext_vector_type(16)));
typedef unsigned u32x4 __attribute__((ext_vector_type(4)));

// ws layout (bytes):
//  Ofrag : [32 s][176 mt][64 lane][16B]        = 5,767,168
//  W0frag: [2 half][32 s][16 nt][64][16B]      = 1,048,576
//  W1frag: [32 s][8 ct][64][16B]               =   262,144
//  Ub    : bf16 [5632][512]  (U + b0 folded)   = 5,767,168
//  Vsw   : bf16 [352][16][512] chunk-XOR sw    = 5,767,168
#define OFRAG_OFF   0
#define W0FRAG_OFF  5767168
#define W1FRAG_OFF  (W0FRAG_OFF + 1048576)
#define UB_OFF      (W1FRAG_OFF + 262144)
#define VSW_OFF     (UB_OFF + 5767168)

// RNE fp32->bf16 via bit ops
__device__ __forceinline__ unsigned bf_rn(float f) {
    unsigned u = __float_as_uint(f);
    return (u + 0x7fffu + ((u >> 16) & 1u)) >> 16;
}
__device__ __forceinline__ unsigned pk_bf16(float lo, float hi) {
    return bf_rn(lo) | (bf_rn(hi) << 16);
}
__device__ __forceinline__ unsigned short f2bf(float f) {
    return (unsigned short)bf_rn(f);
}
__device__ __forceinline__ float bfu_lo(unsigned u) { return __uint_as_float(u << 16); }
__device__ __forceinline__ float bfu_hi(unsigned u) { return __uint_as_float(u & 0xffff0000u); }
__device__ __forceinline__ unsigned cvt_pk(float lo, float hi) {
    unsigned r;
    asm("v_cvt_pk_bf16_f32 %0, %1, %2" : "=v"(r) : "v"(lo), "v"(hi));
    return r;
}

// ---------------------------------------------------------------------------
// k_prep: merged W0/W1/O fragment repack (bf16, fragment-ordered).
// unit < 1024: W0; unit < 1280: W1; else O. 4 wave-units per 256-thr block.
// ---------------------------------------------------------------------------
__global__ __launch_bounds__(256) void k_prep(const float* __restrict__ W0,
                                              const float* __restrict__ W1,
                                              const float* __restrict__ O,
                                              char* __restrict__ ws)
{
    const int unit = blockIdx.x * 4 + (threadIdx.x >> 6);
    const int l = threadIdx.x & 63;
    if (unit < 1280) {
        const float* src; size_t dstoff; int stride;
        if (unit < 1024) {
            int half = unit >> 9, s = (unit >> 4) & 31, nt = unit & 15;
            int k = s*16 + (l >> 5)*8;
            int n = nt*32 + (l & 31);
            src = W0 + (size_t)(half*512 + k) * H0_ + n;
            stride = H0_;
            dstoff = W0FRAG_OFF + (((size_t)(half*32 + s)*16 + nt)*64 + l)*16;
        } else {
            int r = unit - 1024; int s = r >> 3, ct = r & 7;
            int k = s*16 + (l >> 5)*8;
            int n = ct*32 + (l & 31);
            src = W1 + (size_t)k * H1_ + n;
            stride = H1_;
            dstoff = W1FRAG_OFF + (((size_t)(s*8 + ct))*64 + l)*16;
        }
        float f[8];
        #pragma unroll
        for (int j = 0; j < 8; ++j) f[j] = src[(size_t)j * stride];
        u32x4 o = { pk_bf16(f[0],f[1]), pk_bf16(f[2],f[3]), pk_bf16(f[4],f[5]), pk_bf16(f[6],f[7]) };
        *(u32x4*)(ws + dstoff) = o;
    } else {
        const int u = unit - 1280;               // 0..5631 = s*176 + mt
        const int s = u / 176, mt = u % 176;
        const int row = mt*32 + (l & 31);
        const int b  = row / (TM1*K_);
        const int rem = row % (TM1*K_);
        const int t  = rem / K_;
        const int i  = rem % K_;
        const float* src = O + (((size_t)(b*T_ + t + 1)*K_ + i)*DIM_) + s*16 + (l >> 5)*8;
        float4 a = *(const float4*)src;
        float4 c = *(const float4*)(src + 4);
        u32x4 o = { pk_bf16(a.x,a.y), pk_bf16(a.z,a.w), pk_bf16(c.x,c.y), pk_bf16(c.z,c.w) };
        *(u32x4*)(ws + OFRAG_OFF + ((size_t)(s*176 + mt)*64 + l)*16) = o;
    }
}

// ---------------------------------------------------------------------------
// k_uv: [5632 x 512] @ [512 x 1024] -> Ub (bf16, +b0) / Vsw (bf16, chunk-XOR)
// 256-thr block = 4 independent waves; each wave: 64x64 tile, no LDS/barriers,
// 2-step register prefetch from L2-resident frags.
// ---------------------------------------------------------------------------
__global__ __launch_bounds__(256) void k_uv(char* __restrict__ ws,
                                            const float* __restrict__ b0)
{
    const int mb = blockIdx.x;                      // 0..87
    const int t  = threadIdx.x, l = t & 63;
    const int nb = blockIdx.y * 4 + (t >> 6);       // 0..15
    const int half = nb >> 3;
    const char* Ag = ws + OFRAG_OFF + ((size_t)(mb*2)*64 + l)*16;
    const char* Bg = ws + W0FRAG_OFF + (size_t)half*524288 + ((size_t)((nb&7)*2)*64 + l)*16;
    const size_t AS = 176*1024, BS = 16*1024;

    f32x16 acc[2][2];
    #pragma unroll
    for (int p = 0; p < 2; ++p)
        #pragma unroll
        for (int c = 0; c < 2; ++c)
            #pragma unroll
            for (int r = 0; r < 16; ++r) acc[p][c][r] = 0.f;

    u32x4 aA[2], bA[2], aB[2], bB[2];
    #pragma unroll
    for (int p = 0; p < 2; ++p) {
        aA[p] = *(const u32x4*)(Ag + 0*AS + p*1024);
        bA[p] = *(const u32x4*)(Bg + 0*BS + p*1024);
        aB[p] = *(const u32x4*)(Ag + 1*AS + p*1024);
        bB[p] = *(const u32x4*)(Bg + 1*BS + p*1024);
    }

    for (int ss = 0; ss < 32; ss += 2) {
        {
            union { u32x4 u[2]; bf16x8 b[2]; } af, bf;
            af.u[0]=aA[0]; af.u[1]=aA[1]; bf.u[0]=bA[0]; bf.u[1]=bA[1];
            if (ss + 2 < 32) {
                #pragma unroll
                for (int p = 0; p < 2; ++p) {
                    aA[p] = *(const u32x4*)(Ag + (size_t)(ss+2)*AS + p*1024);
                    bA[p] = *(const u32x4*)(Bg + (size_t)(ss+2)*BS + p*1024);
                }
            }
            acc[0][0] = __builtin_amdgcn_mfma_f32_32x32x16_bf16(af.b[0], bf.b[0], acc[0][0], 0,0,0);
            acc[0][1] = __builtin_amdgcn_mfma_f32_32x32x16_bf16(af.b[0], bf.b[1], acc[0][1], 0,0,0);
            acc[1][0] = __builtin_amdgcn_mfma_f32_32x32x16_bf16(af.b[1], bf.b[0], acc[1][0], 0,0,0);
            acc[1][1] = __builtin_amdgcn_mfma_f32_32x32x16_bf16(af.b[1], bf.b[1], acc[1][1], 0,0,0);
        }
        {
            union { u32x4 u[2]; bf16x8 b[2]; } af, bf;
            af.u[0]=aB[0]; af.u[1]=aB[1]; bf.u[0]=bB[0]; bf.u[1]=bB[1];
            if (ss + 3 < 32) {
                #pragma unroll
                for (int p = 0; p < 2; ++p) {
                    aB[p] = *(const u32x4*)(Ag + (size_t)(ss+3)*AS + p*1024);
                    bB[p] = *(const u32x4*)(Bg + (size_t)(ss+3)*BS + p*1024);
                }
            }
            acc[0][0] = __builtin_amdgcn_mfma_f32_32x32x16_bf16(af.b[0], bf.b[0], acc[0][0], 0,0,0);
            acc[0][1] = __builtin_amdgcn_mfma_f32_32x32x16_bf16(af.b[0], bf.b[1], acc[0][1], 0,0,0);
            acc[1][0] = __builtin_amdgcn_mfma_f32_32x32x16_bf16(af.b[1], bf.b[0], acc[1][0], 0,0,0);
            acc[1][1] = __builtin_amdgcn_mfma_f32_32x32x16_bf16(af.b[1], bf.b[1], acc[1][1], 0,0,0);
        }
    }

    #pragma unroll
    for (int p = 0; p < 2; ++p) {
        #pragma unroll
        for (int c = 0; c < 2; ++c) {
            const int col = (nb & 7)*64 + c*32 + (l & 31);
            const float bias = (half == 0) ? b0[col] : 0.f;
            #pragma unroll
            for (int r = 0; r < 16; ++r) {
                const int row = (r & 3) + 8*(r >> 2) + 4*(l >> 5);
                const int M = mb*64 + p*32 + row;
                const float v = acc[p][c][r] + bias;
                if (half == 0) {
                    *(unsigned short*)(ws + UB_OFF + ((size_t)M*512 + col)*2) = f2bf(v);
                } else {
                    const int bt = M >> 4, j = M & 15;
                    const int cc = col >> 3;
                    const int c2 = ((cc ^ (j & 7)) << 3) | (col & 7);
                    *(unsigned short*)(ws + VSW_OFF + ((size_t)(bt*16 + j)*512 + c2)*2) = f2bf(v);
                }
            }
        }
    }
}

// ---------------------------------------------------------------------------
// k_obj: is_obj output (nt stores).
// ---------------------------------------------------------------------------
__global__ __launch_bounds__(256) void k_obj(const float* __restrict__ O,
                                             float* __restrict__ out)
{
    __shared__ float red[16][16];
    __shared__ float fl[16];
    const int bt = blockIdx.x;
    const int b_ = bt / TM1, tt = bt % TM1;
    const int t  = threadIdx.x;
    const int i  = t >> 4, s = t & 15;
    const float* base = O + (((size_t)(b_ * T_ + tt + 1) * K_ + i) * DIM_) + s * 32;
    float sum = 0.f;
    #pragma unroll
    for (int q = 0; q < 8; ++q) {
        float4 v = *(const float4*)(base + q * 4);
        sum += v.x + v.y + v.z + v.w;
    }
    red[i][s] = sum;
    __syncthreads();
    if (t < 16) {
        float f = 0.f;
        #pragma unroll
        for (int s2 = 0; s2 < 16; ++s2) f += red[t][s2];
        fl[t] = fminf(fmaxf(f, 0.f), 1.f);
    }
    __syncthreads();
    const float val = fminf((float)(tt + 1) * fl[t >> 4] * fl[t & 15], 1.f);
    __builtin_nontemporal_store(val, out + (size_t)E_ELEMS + (size_t)bt * 256 + t);
}

// ---------------------------------------------------------------------------
// k_e: e = relu( relu(U_i + V_j) @ W1 + b1 ). Barrier-free main loop, depth-2
// W1 register pipeline (4 rotating banks), nt output stores (keep W1 in L2).
// Block = (bt, ph): 128 pairs x 256 cols, 4 waves (wp,wc), wave 64x128.
// ---------------------------------------------------------------------------
#define EBODY(S, WUSE, WLD, DOLOAD)                                            \
    do {                                                                       \
        if (DOLOAD) {                                                          \
            _Pragma("unroll")                                                  \
            for (int c_ = 0; c_ < 4; ++c_)                                     \
                WLD[c_] = *(const u32x4*)(Wg + (size_t)((S)+2)*8192 + c_*1024);\
        }                                                                      \
        const int vchunk_ = ((S)*2 + kc) ^ (jj & 7);                           \
        u32x4 vu_ = *(const u32x4*)(Vs + jj*1024 + vchunk_*16);                \
        float vf_[8];                                                          \
        _Pragma("unroll")                                                      \
        for (int q_ = 0; q_ < 4; ++q_) {                                       \
            vf_[2*q_] = bfu_lo(vu_[q_]); vf_[2*q_+1] = bfu_hi(vu_[q_]);        \
        }                                                                      \
        bf16x8 afrag_[2];                                                      \
        _Pragma("unroll")                                                      \
        for (int p_ = 0; p_ < 2; ++p_) {                                       \
            const int iloc_ = wp*4 + p_*2 + ih;                                \
            u32x4 uu_ = *(const u32x4*)(Us + iloc_*1024 + (S)*32 + kc*16);     \
            u32x4 o_;                                                          \
            _Pragma("unroll")                                                  \
            for (int q_ = 0; q_ < 4; ++q_) {                                   \
                float h0_ = fmaxf(bfu_lo(uu_[q_]) + vf_[2*q_],   0.f);         \
                float h1_ = fmaxf(bfu_hi(uu_[q_]) + vf_[2*q_+1], 0.f);         \
                o_[q_] = cvt_pk(h0_, h1_);                                     \
            }                                                                  \
            union { u32x4 u; bf16x8 b; } cv_; cv_.u = o_; afrag_[p_] = cv_.b;  \
        }                                                                      \
        union { u32x4 u[4]; bf16x8 b[4]; } wcu_;                               \
        _Pragma("unroll")                                                      \
        for (int c_ = 0; c_ < 4; ++c_) wcu_.u[c_] = WUSE[c_];                  \
        _Pragma("unroll")                                                      \
        for (int p_ = 0; p_ < 2; ++p_)                                         \
            _Pragma("unroll")                                                  \
            for (int c_ = 0; c_ < 4; ++c_)                                     \
                acc[p_][c_] = __builtin_amdgcn_mfma_f32_32x32x16_bf16(         \
                    afrag_[p_], wcu_.b[c_], acc[p_][c_], 0, 0, 0);             \
    } while (0)

__global__ __launch_bounds__(256, 2) void k_e(const char* __restrict__ ws,
                                              const float* __restrict__ b1,
                                              float* __restrict__ out)
{
    __shared__ alignas(16) char lds[24576];
    char* Us = lds;                 // [8][512] bf16
    char* Vs = lds + 8192;          // [16][512] bf16 (chunk-XOR content)

    const int bid = blockIdx.x;     // bt*2 + ph
    const int bt = bid >> 1, ph = bid & 1;
    const int t = threadIdx.x, l = t & 63, w = t >> 6;
    const int wp = w & 1, wc = w >> 1;

    const char* Ug = ws + UB_OFF  + (size_t)(bt*16 + ph*8) * 1024;
    const char* Vg = ws + VSW_OFF + (size_t)bt * 16384;
    const char* Wg = ws + W1FRAG_OFF + (size_t)(wc*4)*1024 + (size_t)l*16;

    #pragma unroll
    for (int r = 0; r < 2; ++r) { int c = t + r*256; *(u32x4*)(Us + c*16) = *(const u32x4*)(Ug + c*16); }
    #pragma unroll
    for (int r = 0; r < 4; ++r) { int c = t + r*256; *(u32x4*)(Vs + c*16) = *(const u32x4*)(Vg + c*16); }
    __syncthreads();

    f32x16 acc[2][4];
    #pragma unroll
    for (int p = 0; p < 2; ++p)
        #pragma unroll
        for (int c = 0; c < 4; ++c)
            #pragma unroll
            for (int r = 0; r < 16; ++r) acc[p][c][r] = 0.f;

    const int jj = l & 15;
    const int kc = l >> 5;
    const int ih = (l >> 4) & 1;

    // W1 pipeline: 4 banks, depth-2 (use bank q at step s, load bank (q+2)&3
    // with step s+2 at the TOP of step s — target bank was consumed at s-2).
    u32x4 wk0[4], wk1[4], wk2[4], wk3[4];
    #pragma unroll
    for (int c = 0; c < 4; ++c) wk0[c] = *(const u32x4*)(Wg + c*1024);
    #pragma unroll
    for (int c = 0; c < 4; ++c) wk1[c] = *(const u32x4*)(Wg + 8192 + c*1024);

    for (int j = 0; j < 8; ++j) {
        const int s = j * 4;
        EBODY(s+0, wk0, wk2, true);
        EBODY(s+1, wk1, wk3, true);
        EBODY(s+2, wk2, wk0, (j < 7));
        EBODY(s+3, wk3, wk1, (j < 7));
    }

    // epilogue: + b1, relu, nt store fp32 (don't pollute L2 with the 90MB out)
    #pragma unroll
    for (int c = 0; c < 4; ++c) {
        const int col = wc*128 + c*32 + (l & 31);
        const float bb = b1[col];
        #pragma unroll
        for (int p = 0; p < 2; ++p) {
            #pragma unroll
            for (int r = 0; r < 16; ++r) {
                const int pair = ph*128 + wp*64 + p*32 + (r & 3) + 8*(r >> 2) + 4*(l >> 5);
                const float v = fmaxf(acc[p][c][r] + bb, 0.f);
                __builtin_nontemporal_store(v, out + ((size_t)bt*256 + pair)*256 + col);
            }
        }
    }
}

// ---------------------------------------------------------------------------
extern "C" void kernel_launch(void* const* d_in, const int* in_sizes, int n_in,
                              void* d_out, int out_size, void* d_ws, size_t ws_size,
                              hipStream_t stream) {
    const float* O  = (const float*)d_in[0];
    const float* W0 = (const float*)d_in[1];
    const float* b0 = (const float*)d_in[2];
    const float* W1 = (const float*)d_in[3];
    const float* b1 = (const float*)d_in[4];
    float* out = (float*)d_out;
    char* ws = (char*)d_ws;

    k_prep<<<1728, 256, 0, stream>>>(W0, W1, O, ws);
    dim3 guv(88, 4);
    k_uv<<<guv, 256, 0, stream>>>(ws, b0);
    k_obj<<<NBT, 256, 0, stream>>>(O, out);
    k_e<<<NBT * 2, 256, 0, stream>>>(ws, b1, out);
}